// Round 1
// baseline (99.907 us; speedup 1.0000x reference)
//
#include <hip/hip_runtime.h>
#include <hip/hip_bf16.h>

// Problem constants
#define PN 4096
#define IN 256
#define HN 64
#define AN 32

// Output layout (FLOAT32 elements), reference return order:
// response_mu (P*I), ability_mu (P*A), ability_logvar (P*A), item_mu (I), item_logvar (I)
#define OFF_RESP 0
#define OFF_AMU  (PN * IN)
#define OFF_ALV  (OFF_AMU + PN * AN)
#define OFF_IMU  (OFF_ALV + PN * AN)
#define OFF_ILV  (OFF_IMU + IN)

// f(x) = elu( elu(x*w1+b1) @ w2 + b2 ) sampled on 128 grid points, x in [0,1].
#define TROWS 128
#define PERS  8              // persons per block

typedef short  s16x8  __attribute__((ext_vector_type(8)));
typedef float  f32x4  __attribute__((ext_vector_type(4)));

__device__ __forceinline__ unsigned short f2bf(float f) {
    union { float f; unsigned int u; } v; v.f = f;
    unsigned int u = v.u;
    u += 0x7FFFu + ((u >> 16) & 1u);
    return (unsigned short)(u >> 16);
}

__device__ __forceinline__ float eluf(float x) {
    return x > 0.0f ? x : (__expf(x) - 1.0f);
}

__device__ __forceinline__ unsigned int pack_bf16(float a, float b) {
    union { __hip_bfloat162 h; unsigned int u; } cv;
    cv.h = __float22bfloat162_rn(make_float2(a, b));
    return cv.u;
}

// ---------------------------------------------------------------------------
// Fully fused kernel: 512 blocks x 256 threads, 8 persons/block, 2 blocks/CU.
// v2 changes vs 98 us baseline (latency-focused; k_fused is serialization-
// bound, ~15 us residual on top of harness fills):
//   - all HBM loads (response/mask/eps/item tables) hoisted to kernel entry
//     so their latency overlaps the weight-staging phase
//   - barriers 9 -> 6: sHMB/sT2 moved OUT of the sTB byte-span (into the
//     dead sW2T tail of region A) so the phase-5->6 region-reuse barrier
//     vanishes; phases 8-10 fused fully in-register (per-wave redundant
//     4-col-tile MFMA for `out`, shfl-based ability sums) -> no sOut/sAS
//     LDS round-trip, no tail barriers
//   - sWB pack stage deleted: phase-5 A-fragments read the f32 scatter bins
//     directly (2x ds_read_b128 + in-reg bf16 pack); sW widened to 16 zeroed
//     rows so M=16 MFMA reads stay in-bounds
// ---------------------------------------------------------------------------
__global__ __launch_bounds__(256, 2) void k_fused(
    const float* __restrict__ response,
    const int* __restrict__ mask,
    const float* __restrict__ w1,
    const float* __restrict__ b1,
    const float* __restrict__ w2,
    const float* __restrict__ b2,
    const float* __restrict__ w3,
    const float* __restrict__ b3,
    const float* __restrict__ w4,
    const float* __restrict__ b4,
    const float* __restrict__ eps_ability,
    const int* __restrict__ item_index,
    const float* __restrict__ eps_item,
    const float* __restrict__ mu_table,
    const float* __restrict__ logvar_table,
    float* __restrict__ out_amu,
    float* __restrict__ out_alv,
    float* __restrict__ out_imu,
    float* __restrict__ out_ilv,
    float* __restrict__ out_resp)
{
    // Region A (27648 B), time-multiplexed with barriers between roles:
    //   role 1: sH1[128][72]us (0..18432) + sW2T[64][72]us (18432..27648)
    //   role 2: sTB[64][136]us (0..17408)  (table, B-operand layout)
    //           sHMB[16][72]us @17408 + sT2[16][72]us @19712  (both inside
    //           the dead sW2T span; disjoint from sTB -> no extra barrier)
    __shared__ __align__(16) unsigned char sRegA[27648];
    __shared__ __align__(16) float sW[16 * 132];     // f32 scatter bins, rows 8..15 stay zero
    __shared__ __align__(16) unsigned short sW3T[64 * 72];
    __shared__ __align__(16) unsigned short sW4T[64 * 72];
    __shared__ float sW1[64], sB1[64], sB2[64], sB3[64], sB4[64];
    __shared__ float sIF[256];
    __shared__ int   sCnt[16];

    unsigned short* sH1  = (unsigned short*)sRegA;              // [128][72]
    unsigned short* sW2T = (unsigned short*)sRegA + 128 * 72;   // [64][72]
    unsigned short* sTB  = (unsigned short*)sRegA;              // [64][136]
    unsigned short* sHMB = (unsigned short*)(sRegA + 17408);    // [16][72]
    unsigned short* sT2  = (unsigned short*)(sRegA + 19712);    // [16][72]

    const int t    = threadIdx.x;
    const int p0   = blockIdx.x * PERS;
    const int wave = t >> 6;
    const int lane = t & 63;
    const int quad = lane >> 4;
    const int r    = lane & 15;

    // ---- phase 0: hoist ALL HBM loads; latency overlaps the staging below ----
    float4 xr[2];
    int4   mr[2];
    #pragma unroll
    for (int k = 0; k < 2; ++k) {
        int vi = t + 256 * k;
        xr[k] = ((const float4*)(response + p0 * IN))[vi];
        mr[k] = ((const int4*)(mask + p0 * IN))[vi];
    }
    // eps_ability for persons 0..7 (quads 0,1 hold the live rows)
    float epsv[4][2] = {{0.f,0.f},{0.f,0.f},{0.f,0.f},{0.f,0.f}};
    if (quad < 2) {
        #pragma unroll
        for (int reg = 0; reg < 4; ++reg)
            #pragma unroll
            for (int ct = 0; ct < 2; ++ct)
                epsv[reg][ct] = eps_ability[(p0 + quad * 4 + reg) * AN + ct * 16 + r];
    }
    int   ii_idx = item_index[t];
    float ii_mu  = mu_table[ii_idx];
    float ii_lv  = logvar_table[ii_idx];
    float ii_eps = eps_item[t];

    // ---- phase 1: stage weights/tables; zero bins ----
    if (t < 64) {
        sW1[t] = w1[t]; sB1[t] = b1[t]; sB2[t] = b2[t];
        sB3[t] = b3[t]; sB4[t] = b4[t];
    }
    for (int base = t * 4; base < 4096; base += 1024) {
        int j = base >> 6, n0 = base & 63;
        float4 v2 = *(const float4*)&w2[base];
        sW2T[(n0 + 0) * 72 + j] = f2bf(v2.x);
        sW2T[(n0 + 1) * 72 + j] = f2bf(v2.y);
        sW2T[(n0 + 2) * 72 + j] = f2bf(v2.z);
        sW2T[(n0 + 3) * 72 + j] = f2bf(v2.w);
        float4 v3 = *(const float4*)&w3[base];
        sW3T[(n0 + 0) * 72 + j] = f2bf(v3.x);
        sW3T[(n0 + 1) * 72 + j] = f2bf(v3.y);
        sW3T[(n0 + 2) * 72 + j] = f2bf(v3.z);
        sW3T[(n0 + 3) * 72 + j] = f2bf(v3.w);
        float4 v4 = *(const float4*)&w4[base];
        sW4T[(n0 + 0) * 72 + j] = f2bf(v4.x);
        sW4T[(n0 + 1) * 72 + j] = f2bf(v4.y);
        sW4T[(n0 + 2) * 72 + j] = f2bf(v4.z);
        sW4T[(n0 + 3) * 72 + j] = f2bf(v4.w);
    }
    {
        sIF[t] = ii_mu + ii_eps * __expf(0.5f * ii_lv);
        if (blockIdx.x == 0) { out_imu[t] = ii_mu; out_ilv[t] = ii_lv; }
    }
    for (int idx = t; idx < 16 * 132; idx += 256) sW[idx] = 0.0f;
    if (t < 16) sCnt[t] = 0;
    __syncthreads();                                   // B1: staging complete

    // ---- phase 2a: h1 grid rows (bf16), all 4 waves (2 threads per row) ----
    {
        int row  = t & 127;
        int half = t >> 7;               // 0/1 -> cols [0,32) / [32,64)
        float xg = (float)row * (1.0f / 127.0f);
        #pragma unroll
        for (int j0 = half * 32; j0 < half * 32 + 32; j0 += 8) {
            uint4 pk;
            pk.x = pack_bf16(eluf(fmaf(xg, sW1[j0+0], sB1[j0+0])),
                             eluf(fmaf(xg, sW1[j0+1], sB1[j0+1])));
            pk.y = pack_bf16(eluf(fmaf(xg, sW1[j0+2], sB1[j0+2])),
                             eluf(fmaf(xg, sW1[j0+3], sB1[j0+3])));
            pk.z = pack_bf16(eluf(fmaf(xg, sW1[j0+4], sB1[j0+4])),
                             eluf(fmaf(xg, sW1[j0+5], sB1[j0+5])));
            pk.w = pack_bf16(eluf(fmaf(xg, sW1[j0+6], sB1[j0+6])),
                             eluf(fmaf(xg, sW1[j0+7], sB1[j0+7])));
            *(uint4*)&sH1[row * 72 + j0] = pk;
        }
    }

    // ---- phase 2b: item scatter from hoisted regs. (wave,k) = one person ----
    #pragma unroll
    for (int k = 0; k < 2; ++k) {
        int person = wave + 4 * k;                    // wave-uniform
        unsigned long long bl0 = __ballot(mr[k].x != 0);
        unsigned long long bl1 = __ballot(mr[k].y != 0);
        unsigned long long bl2 = __ballot(mr[k].z != 0);
        unsigned long long bl3 = __ballot(mr[k].w != 0);
        if (lane == 0)
            sCnt[person] = (int)(__popcll(bl0) + __popcll(bl1) + __popcll(bl2) + __popcll(bl3));
        float xs[4] = {xr[k].x, xr[k].y, xr[k].z, xr[k].w};
        int   ms[4] = {mr[k].x, mr[k].y, mr[k].z, mr[k].w};
        #pragma unroll
        for (int u = 0; u < 4; ++u) {
            if (ms[u]) {
                float kf = xs[u] * 127.0f;
                int kk = (int)kf;
                kk = (kk < 0) ? 0 : ((kk > 126) ? 126 : kk);
                float w = kf - (float)kk;
                atomicAdd(&sW[person * 132 + kk],     1.0f - w);
                atomicAdd(&sW[person * 132 + kk + 1], w);
            }
        }
    }
    __syncthreads();                                   // B2: sH1 + sW + sCnt ready

    // ---- phase 3: table MFMA 128x64 @ 64x64 ; wave owns rows [32w,32w+32) ----
    f32x4 accT[2][4];
    #pragma unroll
    for (int rt = 0; rt < 2; ++rt)
        #pragma unroll
        for (int ct = 0; ct < 4; ++ct)
            accT[rt][ct] = (f32x4){0.f, 0.f, 0.f, 0.f};
    #pragma unroll
    for (int kk = 0; kk < 64; kk += 32) {
        s16x8 af[2], bfr[4];
        #pragma unroll
        for (int rt = 0; rt < 2; ++rt)
            af[rt] = *(const s16x8*)&sH1[(wave * 32 + rt * 16 + r) * 72 + kk + quad * 8];
        #pragma unroll
        for (int ct = 0; ct < 4; ++ct)
            bfr[ct] = *(const s16x8*)&sW2T[(ct * 16 + r) * 72 + kk + quad * 8];
        #pragma unroll
        for (int rt = 0; rt < 2; ++rt)
            #pragma unroll
            for (int ct = 0; ct < 4; ++ct)
                accT[rt][ct] = __builtin_amdgcn_mfma_f32_16x16x32_bf16(
                    af[rt], bfr[ct], accT[rt][ct], 0, 0, 0);
    }
    __syncthreads();   // B3: all waves done reading sH1/sW2T (sTB overlays sH1)

    // ---- phase 4: TB[col][k] = bf16(elu(acc+b2)) ----
    #pragma unroll
    for (int ct = 0; ct < 4; ++ct) {
        int col = ct * 16 + r;
        float bb = sB2[col];
        #pragma unroll
        for (int rt = 0; rt < 2; ++rt)
            #pragma unroll
            for (int reg = 0; reg < 4; ++reg) {
                int krow = wave * 32 + rt * 16 + quad * 4 + reg;
                sTB[col * 136 + krow] = f2bf(eluf(accT[rt][ct][reg] + bb));
            }
    }
    __syncthreads();                                   // B4: table ready

    // ---- phase 5: hid = W(16x128,8 live) @ T(128x64) ; wave owns col-tile 16w
    //      A-fragments packed in-register straight from the f32 bins ----
    s16x8 afW[4];
    #pragma unroll
    for (int s = 0; s < 4; ++s) {
        const float* src = &sW[r * 132 + s * 32 + quad * 8];
        f32x4 lo = *(const f32x4*)src;
        f32x4 hi = *(const f32x4*)(src + 4);
        union { s16x8 v; unsigned int u[4]; } o;
        o.u[0] = pack_bf16(lo[0], lo[1]);
        o.u[1] = pack_bf16(lo[2], lo[3]);
        o.u[2] = pack_bf16(hi[0], hi[1]);
        o.u[3] = pack_bf16(hi[2], hi[3]);
        afW[s] = o.v;
    }
    f32x4 accH = (f32x4){0.f, 0.f, 0.f, 0.f};
    #pragma unroll
    for (int s = 0; s < 4; ++s) {
        s16x8 bfr = *(const s16x8*)&sTB[(wave * 16 + r) * 136 + s * 32 + quad * 8];
        accH = __builtin_amdgcn_mfma_f32_16x16x32_bf16(afW[s], bfr, accH, 0, 0, 0);
    }

    // ---- phase 6: sHMB[person][col] = bf16(hid / max(cnt,1)) ----
    // (sHMB is OUTSIDE the sTB span -> no barrier needed before writing)
    {
        int col = wave * 16 + r;
        #pragma unroll
        for (int reg = 0; reg < 4; ++reg) {
            int person = quad * 4 + reg;              // 8..15 are zeros (sW rows zeroed)
            float c = fmaxf((float)sCnt[person], 1.0f);
            sHMB[person * 72 + col] = f2bf(accH[reg] / c);
        }
    }
    __syncthreads();                                   // B5: hid-mean ready

    // ---- phase 7: t2 = elu(hid @ w3 + b3), wave owns col-tile 16w ----
    f32x4 accA = (f32x4){0.f, 0.f, 0.f, 0.f};
    #pragma unroll
    for (int kk = 0; kk < 64; kk += 32) {
        s16x8 af = *(const s16x8*)&sHMB[r * 72 + kk + quad * 8];
        s16x8 bfr = *(const s16x8*)&sW3T[(wave * 16 + r) * 72 + kk + quad * 8];
        accA = __builtin_amdgcn_mfma_f32_16x16x32_bf16(af, bfr, accA, 0, 0, 0);
    }
    {
        int col = wave * 16 + r;
        float bb = sB3[col];
        #pragma unroll
        for (int reg = 0; reg < 4; ++reg)
            sT2[(quad * 4 + reg) * 72 + col] = f2bf(eluf(accA[reg] + bb));
    }
    __syncthreads();                                   // B6: t2 ready — LAST barrier

    // ---- phase 8: out = t2 @ w4 + b4, per-wave redundant over ALL 4 col-tiles
    //      (8 tiny MFMAs) so the whole epilogue stays in-register ----
    s16x8 afT[2];
    afT[0] = *(const s16x8*)&sT2[r * 72 + 0  + quad * 8];
    afT[1] = *(const s16x8*)&sT2[r * 72 + 32 + quad * 8];
    f32x4 accB0 = (f32x4){0.f,0.f,0.f,0.f};
    f32x4 accB1 = (f32x4){0.f,0.f,0.f,0.f};
    f32x4 accB2 = (f32x4){0.f,0.f,0.f,0.f};
    f32x4 accB3 = (f32x4){0.f,0.f,0.f,0.f};
    #pragma unroll
    for (int kk = 0; kk < 2; ++kk) {
        s16x8 b0 = *(const s16x8*)&sW4T[(0 * 16 + r) * 72 + kk * 32 + quad * 8];
        s16x8 b1 = *(const s16x8*)&sW4T[(1 * 16 + r) * 72 + kk * 32 + quad * 8];
        s16x8 b2v = *(const s16x8*)&sW4T[(2 * 16 + r) * 72 + kk * 32 + quad * 8];
        s16x8 b3v = *(const s16x8*)&sW4T[(3 * 16 + r) * 72 + kk * 32 + quad * 8];
        accB0 = __builtin_amdgcn_mfma_f32_16x16x32_bf16(afT[kk], b0,  accB0, 0, 0, 0);
        accB1 = __builtin_amdgcn_mfma_f32_16x16x32_bf16(afT[kk], b1,  accB1, 0, 0, 0);
        accB2 = __builtin_amdgcn_mfma_f32_16x16x32_bf16(afT[kk], b2v, accB2, 0, 0, 0);
        accB3 = __builtin_amdgcn_mfma_f32_16x16x32_bf16(afT[kk], b3v, accB3, 0, 0, 0);
    }
    float b4v0 = sB4[0 * 16 + r];
    float b4v1 = sB4[1 * 16 + r];
    float b4v2 = sB4[2 * 16 + r];
    float b4v3 = sB4[3 * 16 + r];

    // ---- phase 9 (in-register): amu/alv stores + ability sums via shfl ----
    // wave w stores its column slice: w0 -> amu[0..16), w1 -> amu[16..32),
    // w2 -> alv[0..16), w3 -> alv[16..32). Every wave holds all tiles.
    {
        f32x4 my = accB0; float bmy = b4v0;
        if (wave == 1) { my = accB1; bmy = b4v1; }
        else if (wave == 2) { my = accB2; bmy = b4v2; }
        else if (wave == 3) { my = accB3; bmy = b4v3; }
        if (quad < 2) {
            float* dst = (wave < 2) ? out_amu : out_alv;
            int a = (wave & 1) * 16 + r;
            #pragma unroll
            for (int reg = 0; reg < 4; ++reg)
                dst[(p0 + quad * 4 + reg) * AN + a] = my[reg] + bmy;
        }
    }
    // per-lane partial ability sums; lane (quad q, r) covers persons 4q+reg
    float S0, S1, S2, S3;
    {
        float mu0, mu1, lv0, lv1;
        mu0 = accB0[0] + b4v0; mu1 = accB1[0] + b4v1;
        lv0 = accB2[0] + b4v2; lv1 = accB3[0] + b4v3;
        S0 = mu0 + epsv[0][0] * __expf(0.5f * lv0) + mu1 + epsv[0][1] * __expf(0.5f * lv1);
        mu0 = accB0[1] + b4v0; mu1 = accB1[1] + b4v1;
        lv0 = accB2[1] + b4v2; lv1 = accB3[1] + b4v3;
        S1 = mu0 + epsv[1][0] * __expf(0.5f * lv0) + mu1 + epsv[1][1] * __expf(0.5f * lv1);
        mu0 = accB0[2] + b4v0; mu1 = accB1[2] + b4v1;
        lv0 = accB2[2] + b4v2; lv1 = accB3[2] + b4v3;
        S2 = mu0 + epsv[2][0] * __expf(0.5f * lv0) + mu1 + epsv[2][1] * __expf(0.5f * lv1);
        mu0 = accB0[3] + b4v0; mu1 = accB1[3] + b4v1;
        lv0 = accB2[3] + b4v2; lv1 = accB3[3] + b4v3;
        S3 = mu0 + epsv[3][0] * __expf(0.5f * lv0) + mu1 + epsv[3][1] * __expf(0.5f * lv1);
    }
    #pragma unroll
    for (int off = 1; off < 16; off <<= 1) {
        S0 += __shfl_xor(S0, off);
        S1 += __shfl_xor(S1, off);
        S2 += __shfl_xor(S2, off);
        S3 += __shfl_xor(S3, off);
    }
    // this wave's response persons are p = wave + 4*k3; reg index = wave
    float pw = S0;
    if (wave == 1) pw = S1;
    else if (wave == 2) pw = S2;
    else if (wave == 3) pw = S3;

    // ---- phase 10: response sigmoid, 16B stores (no barrier needed) ----
    #pragma unroll
    for (int k3 = 0; k3 < 2; ++k3) {
        int pl = wave + 4 * k3;
        float a = __shfl(pw, k3 * 16);    // person pl's sum lives in quad k3, reg=wave
        int i0 = lane * 4;
        f32x4 pk;
        #pragma unroll
        for (int u = 0; u < 4; ++u)
            pk[u] = 1.0f / (1.0f + __expf(-(a + sIF[i0 + u])));
        *(f32x4*)&out_resp[(p0 + pl) * IN + i0] = pk;
    }
}

extern "C" void kernel_launch(void* const* d_in, const int* in_sizes, int n_in,
                              void* d_out, int out_size, void* d_ws, size_t ws_size,
                              hipStream_t stream)
{
    const float* response     = (const float*)d_in[0];
    const int*   mask         = (const int*)d_in[1];
    const int*   item_index   = (const int*)d_in[2];
    const float* eps_ability  = (const float*)d_in[3];
    const float* eps_item     = (const float*)d_in[4];
    const float* w1           = (const float*)d_in[5];
    const float* b1           = (const float*)d_in[6];
    const float* w2           = (const float*)d_in[7];
    const float* b2           = (const float*)d_in[8];
    const float* w3           = (const float*)d_in[9];
    const float* b3           = (const float*)d_in[10];
    const float* w4           = (const float*)d_in[11];
    const float* b4           = (const float*)d_in[12];
    const float* mu_table     = (const float*)d_in[13];
    const float* logvar_table = (const float*)d_in[14];

    float* out = (float*)d_out;

    k_fused<<<PN / PERS, 256, 0, stream>>>(
        response, mask, w1, b1, w2, b2, w3, b3, w4, b4,
        eps_ability, item_index, eps_item, mu_table, logvar_table,
        out + OFF_AMU, out + OFF_ALV, out + OFF_IMU, out + OFF_ILV,
        out + OFF_RESP);
}

// Round 2
// 97.528 us; speedup vs baseline: 1.0244x; 1.0244x over previous
//
#include <hip/hip_runtime.h>
#include <hip/hip_bf16.h>

// Problem constants
#define PN 4096
#define IN 256
#define HN 64
#define AN 32

// Output layout (FLOAT32 elements), reference return order:
// response_mu (P*I), ability_mu (P*A), ability_logvar (P*A), item_mu (I), item_logvar (I)
#define OFF_RESP 0
#define OFF_AMU  (PN * IN)
#define OFF_ALV  (OFF_AMU + PN * AN)
#define OFF_IMU  (OFF_ALV + PN * AN)
#define OFF_ILV  (OFF_IMU + IN)

// f(x) = elu( elu(x*w1+b1) @ w2 + b2 ) sampled on 128 grid points, x ∈ [0,1].
#define TROWS 128
#define PERS  8              // persons per block

typedef short  s16x8  __attribute__((ext_vector_type(8)));
typedef float  f32x4  __attribute__((ext_vector_type(4)));

__device__ __forceinline__ unsigned short f2bf(float f) {
    union { float f; unsigned int u; } v; v.f = f;
    unsigned int u = v.u;
    u += 0x7FFFu + ((u >> 16) & 1u);
    return (unsigned short)(u >> 16);
}

__device__ __forceinline__ float eluf(float x) {
    return x > 0.0f ? x : (__expf(x) - 1.0f);
}

__device__ __forceinline__ unsigned int pack_bf16(float a, float b) {
    union { __hip_bfloat162 h; unsigned int u; } cv;
    cv.h = __float22bfloat162_rn(make_float2(a, b));
    return cv.u;
}

// ---------------------------------------------------------------------------
// Fully fused kernel: 512 blocks x 256 threads, 8 persons/block, 2 blocks/CU.
// v3 = v1 (97.9 us structure, fastest measured) + ONE change: all per-person
// HBM loads (response/mask float4s, eps_ability) hoisted to kernel entry so
// their ~200-900 cy latency overlaps the weight-staging phase instead of
// sitting on the post-barrier critical path. v2's barrier-cut/in-register
// epilogue was measured net-negative and is reverted.
//  1. build table T[128][64] = f(grid) via MFMA (all 4 waves on the elu fill)
//  2. scatter items into per-person weight rows W[8][128] (LDS f32 atomics;
//     one person per (wave,k) slice -> cnt needs no atomics, bins never
//     contend across waves)
//  3. hid_mean = (W @ T) / cnt              (MFMA, M=16 with 8 live rows)
//  4. t2 = elu(hid @ w3 + b3)               (MFMA)
//  5. out = t2 @ w4 + b4                    (MFMA)
//  6. amu/alv, abilitysum, item_feat, response sigmoid — all in-block.
// ---------------------------------------------------------------------------
__global__ __launch_bounds__(256, 2) void k_fused(
    const float* __restrict__ response,
    const int* __restrict__ mask,
    const float* __restrict__ w1,
    const float* __restrict__ b1,
    const float* __restrict__ w2,
    const float* __restrict__ b2,
    const float* __restrict__ w3,
    const float* __restrict__ b3,
    const float* __restrict__ w4,
    const float* __restrict__ b4,
    const float* __restrict__ eps_ability,
    const int* __restrict__ item_index,
    const float* __restrict__ eps_item,
    const float* __restrict__ mu_table,
    const float* __restrict__ logvar_table,
    float* __restrict__ out_amu,
    float* __restrict__ out_alv,
    float* __restrict__ out_imu,
    float* __restrict__ out_ilv,
    float* __restrict__ out_resp)
{
    // Region A (27648 B), time-multiplexed with barriers between roles:
    //   role 1: sH1[128][72]us (18432 B) + sW2T[64][72]us (9216 B)
    //   role 2: sTB[64][136]us (17408 B)   (table, B-operand layout)
    //   role 3: sHMB[16][72]us + sT2[16][72]us + sOut[16][68]f32
    __shared__ __align__(16) unsigned char sRegA[27648];
    __shared__ float sW[PERS * 132];                        // f32 scatter bins
    __shared__ __align__(16) unsigned short sWB[16 * 136];  // bf16 W, A-operand (rows 8..15 zero)
    __shared__ __align__(16) unsigned short sW3T[64 * 72];
    __shared__ __align__(16) unsigned short sW4T[64 * 72];
    __shared__ float sW1[64], sB1[64], sB2[64], sB3[64], sB4[64];
    __shared__ float sIF[256];
    __shared__ int   sCnt[16];
    __shared__ float sAS[PERS];

    unsigned short* sH1  = (unsigned short*)sRegA;              // [128][72]
    unsigned short* sW2T = (unsigned short*)sRegA + 128 * 72;   // [64][72]
    unsigned short* sTB  = (unsigned short*)sRegA;              // [64][136]
    unsigned short* sHMB = (unsigned short*)sRegA;              // [16][72]
    unsigned short* sT2  = (unsigned short*)sRegA + 16 * 72;    // [16][72]
    float*          sOut = (float*)(sRegA + 2 * 16 * 72 * 2);   // [16][68]

    const int t    = threadIdx.x;
    const int p0   = blockIdx.x * PERS;
    const int wave = t >> 6;
    const int lane = t & 63;
    const int quad = lane >> 4;
    const int r    = lane & 15;

    // ---- phase 0: hoist per-person HBM loads; latency overlaps staging ----
    float4 xr[2];
    int4   mr[2];
    #pragma unroll
    for (int k = 0; k < 2; ++k) {
        int vi = t + 256 * k;                         // 512 float4 = 8 persons x 256 items
        xr[k] = ((const float4*)(response + p0 * IN))[vi];
        mr[k] = ((const int4*)(mask + p0 * IN))[vi];
    }
    // eps_ability element this thread will need in phase 9 (pl = t>>5, a = t&31)
    float eps_v = eps_ability[(p0 + (t >> 5)) * AN + (t & 31)];

    // ---- phase 1: stage weights/tables; zero bins ----
    if (t < 64) {
        sW1[t] = w1[t]; sB1[t] = b1[t]; sB2[t] = b2[t];
        sB3[t] = b3[t]; sB4[t] = b4[t];
    }
    for (int base = t * 4; base < 4096; base += 1024) {
        int j = base >> 6, n0 = base & 63;
        float4 v2 = *(const float4*)&w2[base];
        sW2T[(n0 + 0) * 72 + j] = f2bf(v2.x);
        sW2T[(n0 + 1) * 72 + j] = f2bf(v2.y);
        sW2T[(n0 + 2) * 72 + j] = f2bf(v2.z);
        sW2T[(n0 + 3) * 72 + j] = f2bf(v2.w);
        float4 v3 = *(const float4*)&w3[base];
        sW3T[(n0 + 0) * 72 + j] = f2bf(v3.x);
        sW3T[(n0 + 1) * 72 + j] = f2bf(v3.y);
        sW3T[(n0 + 2) * 72 + j] = f2bf(v3.z);
        sW3T[(n0 + 3) * 72 + j] = f2bf(v3.w);
        float4 v4 = *(const float4*)&w4[base];
        sW4T[(n0 + 0) * 72 + j] = f2bf(v4.x);
        sW4T[(n0 + 1) * 72 + j] = f2bf(v4.y);
        sW4T[(n0 + 2) * 72 + j] = f2bf(v4.z);
        sW4T[(n0 + 3) * 72 + j] = f2bf(v4.w);
    }
    {
        int idx = item_index[t];
        float mu = mu_table[idx];
        float lv = logvar_table[idx];
        sIF[t] = mu + eps_item[t] * __expf(0.5f * lv);
        if (blockIdx.x == 0) { out_imu[t] = mu; out_ilv[t] = lv; }
    }
    for (int idx = t; idx < PERS * 132; idx += 256) sW[idx] = 0.0f;
    for (int idx = t; idx < 16 * 68; idx += 256) ((unsigned int*)sWB)[idx] = 0u;
    if (t < 16) sCnt[t] = 0;
    __syncthreads();

    // ---- phase 2a: h1 grid rows (bf16), all 4 waves (2 threads per row) ----
    {
        int row  = t & 127;
        int half = t >> 7;               // 0/1 -> cols [0,32) / [32,64)
        float xg = (float)row * (1.0f / 127.0f);
        #pragma unroll
        for (int j0 = half * 32; j0 < half * 32 + 32; j0 += 8) {
            uint4 pk;
            pk.x = pack_bf16(eluf(fmaf(xg, sW1[j0+0], sB1[j0+0])),
                             eluf(fmaf(xg, sW1[j0+1], sB1[j0+1])));
            pk.y = pack_bf16(eluf(fmaf(xg, sW1[j0+2], sB1[j0+2])),
                             eluf(fmaf(xg, sW1[j0+3], sB1[j0+3])));
            pk.z = pack_bf16(eluf(fmaf(xg, sW1[j0+4], sB1[j0+4])),
                             eluf(fmaf(xg, sW1[j0+5], sB1[j0+5])));
            pk.w = pack_bf16(eluf(fmaf(xg, sW1[j0+6], sB1[j0+6])),
                             eluf(fmaf(xg, sW1[j0+7], sB1[j0+7])));
            *(uint4*)&sH1[row * 72 + j0] = pk;
        }
    }

    // ---- phase 2b: item scatter from hoisted regs. (wave,k) slice = one person ----
    #pragma unroll
    for (int k = 0; k < 2; ++k) {
        int person = wave + 4 * k;                    // wave-uniform
        unsigned long long bl0 = __ballot(mr[k].x != 0);
        unsigned long long bl1 = __ballot(mr[k].y != 0);
        unsigned long long bl2 = __ballot(mr[k].z != 0);
        unsigned long long bl3 = __ballot(mr[k].w != 0);
        if (lane == 0)
            sCnt[person] = (int)(__popcll(bl0) + __popcll(bl1) + __popcll(bl2) + __popcll(bl3));
        float xs[4] = {xr[k].x, xr[k].y, xr[k].z, xr[k].w};
        int   ms[4] = {mr[k].x, mr[k].y, mr[k].z, mr[k].w};
        #pragma unroll
        for (int u = 0; u < 4; ++u) {
            if (ms[u]) {
                float kf = xs[u] * 127.0f;
                int kk = (int)kf;
                kk = (kk < 0) ? 0 : ((kk > 126) ? 126 : kk);
                float w = kf - (float)kk;
                atomicAdd(&sW[person * 132 + kk],     1.0f - w);
                atomicAdd(&sW[person * 132 + kk + 1], w);
            }
        }
    }
    __syncthreads();

    // ---- phase 3: table MFMA 128x64 @ 64x64 ; wave owns rows [32w,32w+32) ----
    f32x4 accT[2][4];
    #pragma unroll
    for (int rt = 0; rt < 2; ++rt)
        #pragma unroll
        for (int ct = 0; ct < 4; ++ct)
            accT[rt][ct] = (f32x4){0.f, 0.f, 0.f, 0.f};
    #pragma unroll
    for (int kk = 0; kk < 64; kk += 32) {
        s16x8 af[2], bfr[4];
        #pragma unroll
        for (int rt = 0; rt < 2; ++rt)
            af[rt] = *(const s16x8*)&sH1[(wave * 32 + rt * 16 + r) * 72 + kk + quad * 8];
        #pragma unroll
        for (int ct = 0; ct < 4; ++ct)
            bfr[ct] = *(const s16x8*)&sW2T[(ct * 16 + r) * 72 + kk + quad * 8];
        #pragma unroll
        for (int rt = 0; rt < 2; ++rt)
            #pragma unroll
            for (int ct = 0; ct < 4; ++ct)
                accT[rt][ct] = __builtin_amdgcn_mfma_f32_16x16x32_bf16(
                    af[rt], bfr[ct], accT[rt][ct], 0, 0, 0);
    }
    __syncthreads();   // all waves done reading sH1/sW2T

    // ---- phase 4: TB[col][k] = bf16(elu(acc+b2)) ; W -> bf16 WB (rows 0..7) ----
    #pragma unroll
    for (int ct = 0; ct < 4; ++ct) {
        int col = ct * 16 + r;
        float bb = sB2[col];
        #pragma unroll
        for (int rt = 0; rt < 2; ++rt)
            #pragma unroll
            for (int reg = 0; reg < 4; ++reg) {
                int krow = wave * 32 + rt * 16 + quad * 4 + reg;
                sTB[col * 136 + krow] = f2bf(eluf(accT[rt][ct][reg] + bb));
            }
    }
    #pragma unroll
    for (int idx = t; idx < PERS * 64; idx += 256) {  // 8 rows x 64 dword-pairs
        int row = idx >> 6, kp = (idx & 63) * 2;
        ((unsigned int*)sWB)[row * 68 + (idx & 63)] =
            pack_bf16(sW[row * 132 + kp], sW[row * 132 + kp + 1]);
    }
    __syncthreads();

    // ---- phase 5: hid = W(16x128,8 live) @ T(128x64) ; wave owns col-tile 16w ----
    f32x4 accH = (f32x4){0.f, 0.f, 0.f, 0.f};
    #pragma unroll
    for (int s = 0; s < 4; ++s) {
        s16x8 af = *(const s16x8*)&sWB[r * 136 + s * 32 + quad * 8];
        s16x8 bfr = *(const s16x8*)&sTB[(wave * 16 + r) * 136 + s * 32 + quad * 8];
        accH = __builtin_amdgcn_mfma_f32_16x16x32_bf16(af, bfr, accH, 0, 0, 0);
    }
    __syncthreads();   // all waves done reading sTB (region A reused below)

    // ---- phase 6: sHMB[person][col] = bf16(hid / max(cnt,1)) ----
    {
        int col = wave * 16 + r;
        #pragma unroll
        for (int reg = 0; reg < 4; ++reg) {
            int person = quad * 4 + reg;              // 0..15; rows 8..15 are junk, never stored
            float c = fmaxf((float)sCnt[person], 1.0f);
            sHMB[person * 72 + col] = f2bf(accH[reg] / c);
        }
    }
    __syncthreads();

    // ---- phase 7: t2 = elu(hid @ w3 + b3) ----
    f32x4 accA = (f32x4){0.f, 0.f, 0.f, 0.f};
    #pragma unroll
    for (int kk = 0; kk < 64; kk += 32) {
        s16x8 af = *(const s16x8*)&sHMB[r * 72 + kk + quad * 8];
        s16x8 bfr = *(const s16x8*)&sW3T[(wave * 16 + r) * 72 + kk + quad * 8];
        accA = __builtin_amdgcn_mfma_f32_16x16x32_bf16(af, bfr, accA, 0, 0, 0);
    }
    {
        int col = wave * 16 + r;
        float bb = sB3[col];
        #pragma unroll
        for (int reg = 0; reg < 4; ++reg)
            sT2[(quad * 4 + reg) * 72 + col] = f2bf(eluf(accA[reg] + bb));
    }
    __syncthreads();

    // ---- phase 8: out = t2 @ w4 + b4 -> sOut f32 ----
    f32x4 accB = (f32x4){0.f, 0.f, 0.f, 0.f};
    #pragma unroll
    for (int kk = 0; kk < 64; kk += 32) {
        s16x8 af = *(const s16x8*)&sT2[r * 72 + kk + quad * 8];
        s16x8 bfr = *(const s16x8*)&sW4T[(wave * 16 + r) * 72 + kk + quad * 8];
        accB = __builtin_amdgcn_mfma_f32_16x16x32_bf16(af, bfr, accB, 0, 0, 0);
    }
    {
        int col = wave * 16 + r;
        float bb = sB4[col];
        #pragma unroll
        for (int reg = 0; reg < 4; ++reg)
            sOut[(quad * 4 + reg) * 68 + col] = accB[reg] + bb;
    }
    __syncthreads();

    // ---- phase 9: amu/alv outputs + abilitysum (256 = 8 persons x 32) ----
    {
        int pl = t >> 5, a = t & 31;
        float mu = sOut[pl * 68 + a];
        float lv = sOut[pl * 68 + a + 32];
        out_amu[(p0 + pl) * AN + a] = mu;
        out_alv[(p0 + pl) * AN + a] = lv;
        float partial = mu + eps_v * __expf(0.5f * lv);
        #pragma unroll
        for (int off = 16; off; off >>= 1) partial += __shfl_xor(partial, off);
        if (a == 0) sAS[pl] = partial;
    }
    __syncthreads();

    // ---- phase 10: response sigmoid, 16B stores ----
    #pragma unroll
    for (int k3 = 0; k3 < 2; ++k3) {
        int vi = t + 256 * k3;               // 512 f32x4 = 8 persons x 256 items
        int pl = vi >> 6, i0 = (vi & 63) * 4;
        float a = sAS[pl];
        f32x4 pk;
        #pragma unroll
        for (int u = 0; u < 4; ++u)
            pk[u] = 1.0f / (1.0f + __expf(-(a + sIF[i0 + u])));
        *(f32x4*)&out_resp[(p0 + pl) * IN + i0] = pk;
    }
}

extern "C" void kernel_launch(void* const* d_in, const int* in_sizes, int n_in,
                              void* d_out, int out_size, void* d_ws, size_t ws_size,
                              hipStream_t stream)
{
    const float* response     = (const float*)d_in[0];
    const int*   mask         = (const int*)d_in[1];
    const int*   item_index   = (const int*)d_in[2];
    const float* eps_ability  = (const float*)d_in[3];
    const float* eps_item     = (const float*)d_in[4];
    const float* w1           = (const float*)d_in[5];
    const float* b1           = (const float*)d_in[6];
    const float* w2           = (const float*)d_in[7];
    const float* b2           = (const float*)d_in[8];
    const float* w3           = (const float*)d_in[9];
    const float* b3           = (const float*)d_in[10];
    const float* w4           = (const float*)d_in[11];
    const float* b4           = (const float*)d_in[12];
    const float* mu_table     = (const float*)d_in[13];
    const float* logvar_table = (const float*)d_in[14];

    float* out = (float*)d_out;

    k_fused<<<PN / PERS, 256, 0, stream>>>(
        response, mask, w1, b1, w2, b2, w3, b3, w4, b4,
        eps_ability, item_index, eps_item, mu_table, logvar_table,
        out + OFF_AMU, out + OFF_ALV, out + OFF_IMU, out + OFF_ILV,
        out + OFF_RESP);
}